// Round 3
// baseline (371.752 us; speedup 1.0000x reference)
//
#include <hip/hip_runtime.h>

// Capsule dynamic routing — fused recompute, broadcast lane layout, high TLP.
// u_i:(B,N,DI) f32, w:(1,N,NO,DI,DE) f32, bias:(N,NO,1) f32, r=3.
// Per pass: per (b,n): recompute u_ji (10x16); if has_v: logits += u_ji.v,
// softmax over o; s += c*u_ji (atomics into (o,e,b)); then squash.
// Layouts: logits (N,NO,B), s/v_t (NO,DE,B) -> lane-coalesced in b.
// u read directly from (B,N,DI): per-wave 8 unique b -> 8x16B segments/load.

#define B    256
#define N    1152
#define NO   10
#define DI   8
#define DE   16
#define NTILE  6
#define NTILES 192     // N / NTILE
#define BTILE  32
#define BTILES 8

// ws layout (floats)
#define LG_OFF 0
#define LG_SZ  (N * NO * B)      // 2,949,120
#define S_OFF  (LG_OFF + LG_SZ)
#define S_SZ   (NO * DE * B)     // 40,960
#define VT_OFF (S_OFF + S_SZ)
#define VT_SZ  (NO * DE * B)     // 40,960

// ---------------------------------------------------------------------------
// Fused routing phase. Lane bits: e4 = lane&3, oh = (lane>>2)&1, bb(3b) = rest.
// Each thread owns (b, o-half[5], e-quad[4]); loops NTILE n's.
// Grid: 192 n-tiles x 8 b-tiles = 1536 blocks x 4 waves = 75% occupancy.
// ---------------------------------------------------------------------------
__global__ __launch_bounds__(256)
void routing_kernel(const float* __restrict__ u,
                    const float* __restrict__ w,
                    const float* __restrict__ bias,
                    const float* __restrict__ v_t,
                    float* __restrict__ logits,
                    float* __restrict__ s,
                    const int has_v, const int load_logits) {
    const int tid   = threadIdx.x;
    const int lane  = tid & 63;
    const int e4    = lane & 3;             // e-quad: e = e4*4+j
    const int oh    = (lane >> 2) & 1;      // o-half: o = oh*5+ok
    const int bb    = (tid >> 6) * 8 + ((tid >> 3) & 7);
    const int b     = blockIdx.y * BTILE + bb;
    const int n0    = blockIdx.x * NTILE;
    const int obase = oh * 5;

    // v fragment for the dot (reused across all n) — 20 scalars
    float4 vv[5];
#pragma unroll
    for (int ok = 0; ok < 5; ++ok) vv[ok] = make_float4(0.f, 0.f, 0.f, 0.f);
    if (has_v) {
#pragma unroll
        for (int ok = 0; ok < 5; ++ok) {
            const float* vp = v_t + (size_t)((obase + ok) * DE + e4 * 4) * B + b;
            vv[ok].x = vp[0 * B]; vv[ok].y = vp[1 * B];
            vv[ok].z = vp[2 * B]; vv[ok].w = vp[3 * B];
        }
    }

    float4 acc[5];
#pragma unroll
    for (int ok = 0; ok < 5; ++ok) acc[ok] = make_float4(0.f, 0.f, 0.f, 0.f);

    for (int i = 0; i < NTILE; ++i) {
        const int n = n0 + i;
        // u row: broadcast across oh/e4 lanes, 8 unique 32B segments per wave
        const float* up = u + ((size_t)b * N + n) * DI;
        const float4 u0 = *(const float4*)up;
        const float4 u1 = *(const float4*)(up + 4);
        const float ur[DI] = {u0.x, u0.y, u0.z, u0.w, u1.x, u1.y, u1.z, u1.w};

        // recompute u_ji for this thread's (o-half, e-quad)
        const float* wp = w + ((size_t)n * NO + obase) * (DI * DE) + e4 * 4;
        float4 uji[5];
#pragma unroll
        for (int ok = 0; ok < 5; ++ok) {
            const float bv = bias[n * NO + obase + ok];
            float4 a = make_float4(bv, bv, bv, bv);
            const float* wo = wp + ok * (DI * DE);
#pragma unroll
            for (int d = 0; d < DI; ++d) {
                const float4 w4 = *(const float4*)(wo + d * DE);
                a.x += ur[d] * w4.x; a.y += ur[d] * w4.y;
                a.z += ur[d] * w4.z; a.w += ur[d] * w4.w;
            }
            uji[ok] = a;
        }

        float c[5];
        if (has_v) {
            float lg[5];
#pragma unroll
            for (int ok = 0; ok < 5; ++ok) {
                float dt = uji[ok].x * vv[ok].x + uji[ok].y * vv[ok].y
                         + uji[ok].z * vv[ok].z + uji[ok].w * vv[ok].w;
                dt += __shfl_xor(dt, 1);        // butterfly over e4 bits
                dt += __shfl_xor(dt, 2);        // -> full sum over e=0..15
                const size_t li = (size_t)(n * NO + obase + ok) * B + b;
                const float old = load_logits ? logits[li] : 0.f;
                lg[ok] = old + dt;
            }
            if (e4 == 0) {
#pragma unroll
                for (int ok = 0; ok < 5; ++ok)
                    logits[(size_t)(n * NO + obase + ok) * B + b] = lg[ok];
            }
            // softmax over all 10 o (exchange with other o-half: lane bit 2)
            float m = lg[0];
#pragma unroll
            for (int ok = 1; ok < 5; ++ok) m = fmaxf(m, lg[ok]);
            m = fmaxf(m, __shfl_xor(m, 4));
            float p[5], sl = 0.f;
#pragma unroll
            for (int ok = 0; ok < 5; ++ok) { p[ok] = __expf(lg[ok] - m); sl += p[ok]; }
            sl += __shfl_xor(sl, 4);
            const float inv = 1.f / sl;
#pragma unroll
            for (int ok = 0; ok < 5; ++ok) c[ok] = p[ok] * inv;
        } else {
#pragma unroll
            for (int ok = 0; ok < 5; ++ok) c[ok] = 0.1f;   // softmax of zeros
        }

#pragma unroll
        for (int ok = 0; ok < 5; ++ok) {
            acc[ok].x += c[ok] * uji[ok].x; acc[ok].y += c[ok] * uji[ok].y;
            acc[ok].z += c[ok] * uji[ok].z; acc[ok].w += c[ok] * uji[ok].w;
        }
    }

    // s (o,e,b) += acc ; 192-way contention per address, spread in time
#pragma unroll
    for (int ok = 0; ok < 5; ++ok) {
        float* sp = s + (size_t)((obase + ok) * DE + e4 * 4) * B + b;
        atomicAdd(sp + 0 * B, acc[ok].x);
        atomicAdd(sp + 1 * B, acc[ok].y);
        atomicAdd(sp + 2 * B, acc[ok].z);
        atomicAdd(sp + 3 * B, acc[ok].w);
    }
}

// ---------------------------------------------------------------------------
// Squash: v = ||s||/(1+||s||^2) * s. Lane bits 0-3 = e -> in-wave norm reduce.
// Writes v_t (NO,DE,B) for next routing pass and out (B,NO,DE).
// ---------------------------------------------------------------------------
__global__ __launch_bounds__(256)
void squash_kernel(const float* __restrict__ s,
                   float* __restrict__ v_t,
                   float* __restrict__ out) {
    const int g = blockIdx.x * 256 + threadIdx.x;   // < NO*DE*B = 40960
    const int e = g & 15;
    const int b = (g >> 4) & 255;
    const int o = g >> 12;
    const float sv = s[(size_t)(o * DE + e) * B + b];
    float nsq = sv * sv;
#pragma unroll
    for (int msk = 1; msk <= 8; msk <<= 1) nsq += __shfl_xor(nsq, msk);
    const float nrm   = sqrtf(nsq);
    const float scale = nrm / (1.f + nsq);
    const float val   = sv * scale;
    v_t[(size_t)(o * DE + e) * B + b] = val;
    out[(size_t)(b * NO + o) * DE + e] = val;
}

extern "C" void kernel_launch(void* const* d_in, const int* in_sizes, int n_in,
                              void* d_out, int out_size, void* d_ws, size_t ws_size,
                              hipStream_t stream) {
    const float* u    = (const float*)d_in[0];
    const float* w    = (const float*)d_in[1];   // (N,NO,DI,DE)
    const float* bias = (const float*)d_in[2];   // (N,NO)
    // d_in[3] = r, static 3

    float* wsf    = (float*)d_ws;
    float* logits = wsf + LG_OFF;
    float* s      = wsf + S_OFF;
    float* v_t    = wsf + VT_OFF;
    float* out    = (float*)d_out;

    for (int it = 0; it < 3; ++it) {
        hipMemsetAsync(s, 0, (size_t)S_SZ * sizeof(float), stream);
        routing_kernel<<<dim3(NTILES, BTILES), 256, 0, stream>>>(
            u, w, bias, v_t, logits, s, it > 0, it > 1);
        squash_kernel<<<(NO * DE * B) / 256, 256, 0, stream>>>(s, v_t, out);
    }
}

// Round 4
// 317.620 us; speedup vs baseline: 1.1704x; 1.1704x over previous
//
#include <hip/hip_runtime.h>

// Capsule dynamic routing — fused recompute, no logits buffer, no atomics.
// u_i:(B,N,DI) f32, w:(1,N,NO,DI,DE) f32, bias:(N,NO,1) f32, r=3.
// Key identity: logits_r = sum_{k<r} u_ji . v_k = u_ji . vsum  (dot is linear,
// and since u_ji includes bias, the bias*sum_e(vsum) term is included too).
// Per pass: per (b,n): recompute u_ji; if has_v: lg = u_ji.vsum, softmax over o;
// s_part[tile] += c*u_ji (plain stores). squash: reduce tiles, v, vsum += v.

#define B    256
#define N    1152
#define NO   10
#define DI   8
#define DE   16
#define NTILE  16
#define NTILES 72      // N / NTILE
#define BTILE  32
#define BTILES 8

// ws layout (floats)
#define SP_OFF 0
#define SP_SZ  (NTILES * B * NO * DE)   // 2,949,120 (11.8 MB)
#define VS_OFF (SP_OFF + SP_SZ)
#define VS_SZ  (NO * DE * B)            // 40,960

// ---------------------------------------------------------------------------
// Routing pass. Lane bits: e4 = lane&3, oh = (lane>>2)&1, bb(3b) = lane>>3;
// bb extended by wave id -> 32 b per block. Each thread owns (b, o-half[5],
// e-quad[4]); loops NTILE n's. Grid: 72 n-tiles x 8 b-tiles.
// ---------------------------------------------------------------------------
__global__ __launch_bounds__(256)
void routing_kernel(const float* __restrict__ u,
                    const float* __restrict__ w,
                    const float* __restrict__ bias,
                    const float* __restrict__ vsum,
                    float* __restrict__ s_part,
                    const int has_v) {
    const int tid   = threadIdx.x;
    const int lane  = tid & 63;
    const int e4    = lane & 3;             // e-quad: e = e4*4+j
    const int oh    = (lane >> 2) & 1;      // o-half: o = oh*5+ok
    const int bb    = (tid >> 6) * 8 + ((tid >> 3) & 7);
    const int b     = blockIdx.y * BTILE + bb;
    const int n0    = blockIdx.x * NTILE;
    const int obase = oh * 5;

    // vsum fragment (reused across all n) — 20 scalars
    float4 vv[5];
#pragma unroll
    for (int ok = 0; ok < 5; ++ok) vv[ok] = make_float4(0.f, 0.f, 0.f, 0.f);
    if (has_v) {
#pragma unroll
        for (int ok = 0; ok < 5; ++ok) {
            const float* vp = vsum + (size_t)((obase + ok) * DE + e4 * 4) * B + b;
            vv[ok].x = vp[0 * B]; vv[ok].y = vp[1 * B];
            vv[ok].z = vp[2 * B]; vv[ok].w = vp[3 * B];
        }
    }

    float4 acc[5];
#pragma unroll
    for (int ok = 0; ok < 5; ++ok) acc[ok] = make_float4(0.f, 0.f, 0.f, 0.f);

    for (int i = 0; i < NTILE; ++i) {
        const int n = n0 + i;
        const float* up = u + ((size_t)b * N + n) * DI;
        const float4 u0 = *(const float4*)up;
        const float4 u1 = *(const float4*)(up + 4);
        const float ur[DI] = {u0.x, u0.y, u0.z, u0.w, u1.x, u1.y, u1.z, u1.w};

        // recompute u_ji for this thread's (o-half, e-quad); w is b-independent
        // -> broadcast across the 8 bb lanes (2x64B segments per wave-load).
        const float* wp = w + ((size_t)n * NO + obase) * (DI * DE) + e4 * 4;
        float4 uji[5];
#pragma unroll
        for (int ok = 0; ok < 5; ++ok) {
            const float bv = bias[n * NO + obase + ok];
            float4 a = make_float4(bv, bv, bv, bv);
            const float* wo = wp + ok * (DI * DE);
#pragma unroll
            for (int d = 0; d < DI; ++d) {
                const float4 w4 = *(const float4*)(wo + d * DE);
                a.x += ur[d] * w4.x; a.y += ur[d] * w4.y;
                a.z += ur[d] * w4.z; a.w += ur[d] * w4.w;
            }
            uji[ok] = a;
        }

        float c[5];
        if (has_v) {
            float lg[5];
#pragma unroll
            for (int ok = 0; ok < 5; ++ok) {
                float dt = uji[ok].x * vv[ok].x + uji[ok].y * vv[ok].y
                         + uji[ok].z * vv[ok].z + uji[ok].w * vv[ok].w;
                dt += __shfl_xor(dt, 1);        // butterfly over e4 bits
                dt += __shfl_xor(dt, 2);        // -> full sum over e=0..15
                lg[ok] = dt;
            }
            // softmax over all 10 o (exchange with other o-half: lane bit 2)
            float m = lg[0];
#pragma unroll
            for (int ok = 1; ok < 5; ++ok) m = fmaxf(m, lg[ok]);
            m = fmaxf(m, __shfl_xor(m, 4));
            float p[5], sl = 0.f;
#pragma unroll
            for (int ok = 0; ok < 5; ++ok) { p[ok] = __expf(lg[ok] - m); sl += p[ok]; }
            sl += __shfl_xor(sl, 4);
            const float inv = 1.f / sl;
#pragma unroll
            for (int ok = 0; ok < 5; ++ok) c[ok] = p[ok] * inv;
        } else {
#pragma unroll
            for (int ok = 0; ok < 5; ++ok) c[ok] = 0.1f;   // softmax of zeros
        }

#pragma unroll
        for (int ok = 0; ok < 5; ++ok) {
            acc[ok].x += c[ok] * uji[ok].x; acc[ok].y += c[ok] * uji[ok].y;
            acc[ok].z += c[ok] * uji[ok].z; acc[ok].w += c[ok] * uji[ok].w;
        }
    }

    // deterministic per-tile partial: s_part[tile][b][o][e], float4 over e
    float* sp = s_part + (((size_t)blockIdx.x * B + b) * NO + obase) * DE + e4 * 4;
#pragma unroll
    for (int ok = 0; ok < 5; ++ok)
        *(float4*)(sp + ok * DE) = acc[ok];
}

// ---------------------------------------------------------------------------
// Squash: s = sum_tiles s_part; v = ||s||/(1+||s||^2)*s; out = v; vsum += v.
// g = (b*NO+o)*DE+e -> lane bits 0-3 = e for the in-wave norm reduction.
// ---------------------------------------------------------------------------
__global__ __launch_bounds__(256)
void squash_kernel(const float* __restrict__ s_part,
                   float* __restrict__ vsum,
                   float* __restrict__ out,
                   const int accum) {
    const int g = blockIdx.x * 256 + threadIdx.x;   // < B*NO*DE = 40960
    const int e = g & 15;
    const int bo = g >> 4;          // b*NO + o
    const int o = bo % NO;
    const int b = bo / NO;

    float s = 0.f;
#pragma unroll
    for (int t = 0; t < NTILES; ++t)
        s += s_part[(size_t)t * (B * NO * DE) + g];

    float nsq = s * s;
#pragma unroll
    for (int msk = 1; msk <= 8; msk <<= 1) nsq += __shfl_xor(nsq, msk);
    const float nrm   = sqrtf(nsq);
    const float scale = nrm / (1.f + nsq);
    const float val   = s * scale;

    out[g] = val;                                    // out is (B,NO,DE) == g
    float* vp = vsum + (size_t)(o * DE + e) * B + b; // (NO,DE,B) for routing
    *vp = accum ? (*vp + val) : val;
}

extern "C" void kernel_launch(void* const* d_in, const int* in_sizes, int n_in,
                              void* d_out, int out_size, void* d_ws, size_t ws_size,
                              hipStream_t stream) {
    const float* u    = (const float*)d_in[0];
    const float* w    = (const float*)d_in[1];   // (N,NO,DI,DE)
    const float* bias = (const float*)d_in[2];   // (N,NO)
    // d_in[3] = r, static 3

    float* wsf    = (float*)d_ws;
    float* s_part = wsf + SP_OFF;
    float* vsum   = wsf + VS_OFF;
    float* out    = (float*)d_out;

    for (int it = 0; it < 3; ++it) {
        routing_kernel<<<dim3(NTILES, BTILES), 256, 0, stream>>>(
            u, w, bias, vsum, s_part, it > 0);
        squash_kernel<<<(B * NO * DE) / 256, 256, 0, stream>>>(
            s_part, vsum, out, it > 0);
    }
}

// Round 5
// 255.571 us; speedup vs baseline: 1.4546x; 1.2428x over previous
//
#include <hip/hip_runtime.h>

// Capsule dynamic routing — fused recompute, no logits buffer, no atomics.
// u_i:(B,N,DI) f32, w:(1,N,NO,DI,DE) f32, bias:(N,NO,1) f32, r=3.
// Identity: logits_r = u_ji . (sum_{k<r} v_k) = u_ji . vsum (dot is linear;
// u_ji includes bias so the bias*sum_e term is folded in automatically).
// Per pass: per (b,n): recompute u_ji; if has_v: lg = u_ji.vsum, softmax over o;
// s_part[tile] = sum_n c*u_ji (plain stores). squash: reduce tiles, vsum += v.
// R5: 2304 blocks x 2 waves (occupancy 18->~55%), vsum in (B,NO,DE) layout
// so both its routing loads and squash stores are dense float4/coalesced.

#define B    256
#define N    1152
#define NO   10
#define DI   8
#define DE   16
#define NTILE  8
#define NTILES 144     // N / NTILE
#define BTILE  16
#define BTILES 16
#define THREADS 128

// ws layout (floats)
#define SP_OFF 0
#define SP_SZ  (NTILES * B * NO * DE)   // 5,898,240 (23.6 MB)
#define VS_OFF (SP_OFF + SP_SZ)
#define VS_SZ  (B * NO * DE)            // 40,960

// ---------------------------------------------------------------------------
// Routing pass. Lane bits: e4 = lane&3, oh = (lane>>2)&1, bb = (wave<<3)|(lane>>3).
// Each thread owns (b, o-half[5], e-quad[4]); loops NTILE n's.
// Grid: 144 n-tiles x 16 b-tiles = 2304 blocks x 2 waves.
// ---------------------------------------------------------------------------
__global__ __launch_bounds__(THREADS)
void routing_kernel(const float* __restrict__ u,
                    const float* __restrict__ w,
                    const float* __restrict__ bias,
                    const float* __restrict__ vsum,
                    float* __restrict__ s_part,
                    const int has_v) {
    const int tid   = threadIdx.x;
    const int lane  = tid & 63;
    const int e4    = lane & 3;             // e-quad: e = e4*4+j
    const int oh    = (lane >> 2) & 1;      // o-half: o = oh*5+ok
    const int bb    = (tid >> 6) * 8 + ((tid >> 3) & 7);
    const int b     = blockIdx.y * BTILE + bb;
    const int n0    = blockIdx.x * NTILE;
    const int obase = oh * 5;

    // vsum fragment (reused across all n): dense float4 from (B,NO,DE)
    float4 vv[5];
#pragma unroll
    for (int ok = 0; ok < 5; ++ok) vv[ok] = make_float4(0.f, 0.f, 0.f, 0.f);
    if (has_v) {
#pragma unroll
        for (int ok = 0; ok < 5; ++ok)
            vv[ok] = *(const float4*)(vsum + ((size_t)b * NO + obase + ok) * DE + e4 * 4);
    }

    float4 acc[5];
#pragma unroll
    for (int ok = 0; ok < 5; ++ok) acc[ok] = make_float4(0.f, 0.f, 0.f, 0.f);

    for (int i = 0; i < NTILE; ++i) {
        const int n = n0 + i;
        const float* up = u + ((size_t)b * N + n) * DI;
        const float4 u0 = *(const float4*)up;
        const float4 u1 = *(const float4*)(up + 4);
        const float ur[DI] = {u0.x, u0.y, u0.z, u0.w, u1.x, u1.y, u1.z, u1.w};

        // recompute u_ji for this thread's (o-half, e-quad); w is b-independent
        // -> broadcast across the 8 bb lanes (2x64B segments per wave-load).
        const float* wp = w + ((size_t)n * NO + obase) * (DI * DE) + e4 * 4;
        float4 uji[5];
#pragma unroll
        for (int ok = 0; ok < 5; ++ok) {
            const float bv = bias[n * NO + obase + ok];
            float4 a = make_float4(bv, bv, bv, bv);
            const float* wo = wp + ok * (DI * DE);
#pragma unroll
            for (int d = 0; d < DI; ++d) {
                const float4 w4 = *(const float4*)(wo + d * DE);
                a.x += ur[d] * w4.x; a.y += ur[d] * w4.y;
                a.z += ur[d] * w4.z; a.w += ur[d] * w4.w;
            }
            uji[ok] = a;
        }

        float c[5];
        if (has_v) {
            float lg[5];
#pragma unroll
            for (int ok = 0; ok < 5; ++ok) {
                float dt = uji[ok].x * vv[ok].x + uji[ok].y * vv[ok].y
                         + uji[ok].z * vv[ok].z + uji[ok].w * vv[ok].w;
                dt += __shfl_xor(dt, 1);        // butterfly over e4 bits
                dt += __shfl_xor(dt, 2);        // -> full sum over e=0..15
                lg[ok] = dt;
            }
            // softmax over all 10 o (exchange with other o-half: lane bit 2)
            float m = lg[0];
#pragma unroll
            for (int ok = 1; ok < 5; ++ok) m = fmaxf(m, lg[ok]);
            m = fmaxf(m, __shfl_xor(m, 4));
            float p[5], sl = 0.f;
#pragma unroll
            for (int ok = 0; ok < 5; ++ok) { p[ok] = __expf(lg[ok] - m); sl += p[ok]; }
            sl += __shfl_xor(sl, 4);
            const float inv = 1.f / sl;
#pragma unroll
            for (int ok = 0; ok < 5; ++ok) c[ok] = p[ok] * inv;
        } else {
#pragma unroll
            for (int ok = 0; ok < 5; ++ok) c[ok] = 0.1f;   // softmax of zeros
        }

#pragma unroll
        for (int ok = 0; ok < 5; ++ok) {
            acc[ok].x += c[ok] * uji[ok].x; acc[ok].y += c[ok] * uji[ok].y;
            acc[ok].z += c[ok] * uji[ok].z; acc[ok].w += c[ok] * uji[ok].w;
        }
    }

    // deterministic per-tile partial: s_part[tile][b][o][e], float4 over e
    float* sp = s_part + (((size_t)blockIdx.x * B + b) * NO + obase) * DE + e4 * 4;
#pragma unroll
    for (int ok = 0; ok < 5; ++ok)
        *(float4*)(sp + ok * DE) = acc[ok];
}

// ---------------------------------------------------------------------------
// Squash: s = sum_tiles s_part; v = ||s||/(1+||s||^2)*s; out = v; vsum += v.
// g = (b*NO+o)*DE+e -> lane bits 0-3 = e for the in-wave norm reduction.
// All loads/stores coalesced (g-linear).
// ---------------------------------------------------------------------------
__global__ __launch_bounds__(256)
void squash_kernel(const float* __restrict__ s_part,
                   float* __restrict__ vsum,
                   float* __restrict__ out,
                   const int accum) {
    const int g = blockIdx.x * 256 + threadIdx.x;   // < B*NO*DE = 40960

    float s = 0.f;
#pragma unroll 16
    for (int t = 0; t < NTILES; ++t)
        s += s_part[(size_t)t * (B * NO * DE) + g];

    float nsq = s * s;
#pragma unroll
    for (int msk = 1; msk <= 8; msk <<= 1) nsq += __shfl_xor(nsq, msk);
    const float nrm   = sqrtf(nsq);
    const float scale = nrm / (1.f + nsq);
    const float val   = s * scale;

    out[g]  = val;                       // (B,NO,DE)
    vsum[g] = accum ? (vsum[g] + val) : val;
}

extern "C" void kernel_launch(void* const* d_in, const int* in_sizes, int n_in,
                              void* d_out, int out_size, void* d_ws, size_t ws_size,
                              hipStream_t stream) {
    const float* u    = (const float*)d_in[0];
    const float* w    = (const float*)d_in[1];   // (N,NO,DI,DE)
    const float* bias = (const float*)d_in[2];   // (N,NO)
    // d_in[3] = r, static 3

    float* wsf    = (float*)d_ws;
    float* s_part = wsf + SP_OFF;
    float* vsum   = wsf + VS_OFF;
    float* out    = (float*)d_out;

    for (int it = 0; it < 3; ++it) {
        routing_kernel<<<dim3(NTILES, BTILES), THREADS, 0, stream>>>(
            u, w, bias, vsum, s_part, it > 0);
        squash_kernel<<<(B * NO * DE) / 256, 256, 0, stream>>>(
            s_part, vsum, out, it > 0);
    }
}